// Round 3
// baseline (483.318 us; speedup 1.0000x reference)
//
#include <hip/hip_runtime.h>

// NMS 3x3, replicate pad, strict >, max seeded at 0 (center tap zeroed).
// x: (8, 32, 512, 512) fp32. out = x * (x > max(0, 8 neighbors)).
//
// Streaming wave-per-row-strip design, v2: depth-2 register prefetch.
// One wave owns a full 512-wide row (8 cols/lane as 2x float4) and streams
// a 32-row chunk. 4-slot ring of raw rows; at output row r we ISSUE the
// load of row r+3 and consume loads two iterations after issue, with all
// loads issued BEFORE the iteration's stores -> the vmcnt wait for a row's
// data never forces nontemporal-store retirement (v1's serializer: its
// load->wait immediately after stores was an effective vmcnt(0), ~2900
// cy/row). nt stores keep the 256 MiB input L3-resident (FETCH ~halved).
// Horizontal neighbors: in-register + __shfl at lane seams. Replicate pad
// via clamped row/col: clamped neighbor == center -> strict > fails -> 0,
// matching the reference exactly.

#define IMG_W 512
#define IMG_H 512
#define NPLANES 256          // 8 * 32
#define CHUNK 32             // rows per wave-task
#define THREADS 256          // 4 waves per block
#define WAVES_PER_BLOCK (THREADS / 64)
#define CHUNKS_PER_PLANE (IMG_H / CHUNK)   // 16

typedef float v4f __attribute__((ext_vector_type(4)));

static_assert(IMG_W == 64 * 8, "one wave covers a full row at 8 floats/lane");
static_assert(IMG_H % CHUNK == 0, "chunks divide evenly");
static_assert(CHUNK % 4 == 0, "ring phase aligned across chunks");

__device__ __forceinline__ void load_row(const float* __restrict__ base, int r,
                                         float (&d)[8]) {
    const v4f a = *(const v4f*)(base + (size_t)r * IMG_W);
    const v4f b = *(const v4f*)(base + (size_t)r * IMG_W + 4);
    d[0] = a.x; d[1] = a.y; d[2] = a.z; d[3] = a.w;
    d[4] = b.x; d[5] = b.y; d[6] = b.z; d[7] = b.w;
}

// lr[i] = max(left_i, right_i) (center excluded); hm[i] = max(l,c,r).
__device__ __forceinline__ void row_stats(const float (&d)[8], int lane,
                                          float (&lr)[8], float (&hm)[8]) {
    float lnb = __shfl_up(d[7], 1);          // lane-1's col 8l-1
    lnb = (lane == 0) ? d[0] : lnb;          // replicate col 0
    float rnb = __shfl_down(d[0], 1);        // lane+1's col 8l+8
    rnb = (lane == 63) ? d[7] : rnb;         // replicate col 511

    lr[0] = fmaxf(lnb,  d[1]);
    lr[1] = fmaxf(d[0], d[2]);
    lr[2] = fmaxf(d[1], d[3]);
    lr[3] = fmaxf(d[2], d[4]);
    lr[4] = fmaxf(d[3], d[5]);
    lr[5] = fmaxf(d[4], d[6]);
    lr[6] = fmaxf(d[5], d[7]);
    lr[7] = fmaxf(d[6], rnb);
#pragma unroll
    for (int i = 0; i < 8; ++i) hm[i] = fmaxf(lr[i], d[i]);
}

__global__ __launch_bounds__(THREADS, 4)
void nms3x3_kernel(const float* __restrict__ x, float* __restrict__ out) {
    const int wid   = blockIdx.x * WAVES_PER_BLOCK + (threadIdx.x >> 6);
    const int lane  = threadIdx.x & 63;
    const int plane = wid / CHUNKS_PER_PLANE;
    const int chunk = wid % CHUNKS_PER_PLANE;
    const int r0    = chunk * CHUNK;           // multiple of 32 -> ring phase 0

    const float* img  = x   + (size_t)plane * IMG_H * IMG_W + lane * 8;
    float*       oimg = out + (size_t)plane * IMG_H * IMG_W + lane * 8;

    // Ring buffers. For output row r (k = r - r0):
    //   rowd[(k+0)&3] = raw row r        rowd[(k+1)&3] = raw row r+1
    //   rowd[(k+2)&3] = raw row r+2      load issued here: row r+3 -> (k+3)&3
    //   hmR[(k+3)&3]  = hm(r-1)          hmR[(k+1)&3] = hm(r+1) (made this iter)
    //   lrR[k&1]      = lr(r)
    float rowd[4][8];
    float hmR[4][8];
    float lrR[2][8];

    // Prologue: issue 4 row loads back-to-back, then compute stats.
    load_row(img, (r0 > 0) ? r0 - 1 : 0, rowd[3]);   // row r0-1 (clamped)
    load_row(img, r0,     rowd[0]);
    load_row(img, r0 + 1, rowd[1]);
    load_row(img, r0 + 2, rowd[2]);                  // r0+2 <= 482 < 512
    {
        float junk[8];
        row_stats(rowd[3], lane, junk, hmR[3]);      // hm(r0-1)
    }
    row_stats(rowd[0], lane, lrR[0], hmR[0]);        // lr/hm(r0)

#pragma unroll
    for (int k = 0; k < CHUNK; ++k) {
        const int r = r0 + k;

        // Issue prefetch of row r+3 (skip the 2 tail loads that are never used).
        if (k < CHUNK - 2) {
            int rf = r + 3;
            rf = (rf < IMG_H) ? rf : IMG_H - 1;
            load_row(img, rf, rowd[(k + 3) & 3]);
        }

        // Stats of row r+1 (its load was issued 2 iterations ago).
        row_stats(rowd[(k + 1) & 3], lane, lrR[(k + 1) & 1], hmR[(k + 1) & 3]);

        // Output row r.
        float o[8];
#pragma unroll
        for (int i = 0; i < 8; ++i) {
            float m = fmaxf(fmaxf(hmR[(k + 3) & 3][i], hmR[(k + 1) & 3][i]),
                            lrR[k & 1][i]);
            m = fmaxf(m, 0.0f);                      // center tap zeroed
            const float c = rowd[k & 3][i];
            o[i] = (c > m) ? c : 0.0f;
        }

        const v4f oa = { o[0], o[1], o[2], o[3] };
        const v4f ob = { o[4], o[5], o[6], o[7] };
        __builtin_nontemporal_store(oa, (v4f*)(oimg + (size_t)r * IMG_W));
        __builtin_nontemporal_store(ob, (v4f*)(oimg + (size_t)r * IMG_W + 4));
    }
}

extern "C" void kernel_launch(void* const* d_in, const int* in_sizes, int n_in,
                              void* d_out, int out_size, void* d_ws, size_t ws_size,
                              hipStream_t stream) {
    const float* x = (const float*)d_in[0];
    float* out     = (float*)d_out;
    const int total_waves = NPLANES * CHUNKS_PER_PLANE;        // 4096
    dim3 grid(total_waves / WAVES_PER_BLOCK);                  // 1024 blocks
    nms3x3_kernel<<<grid, dim3(THREADS), 0, stream>>>(x, out);
}

// Round 4
// 444.781 us; speedup vs baseline: 1.0866x; 1.0866x over previous
//
#include <hip/hip_runtime.h>

// NMS 3x3, replicate pad, strict >, max seeded at 0 (center tap zeroed).
// x: (8, 32, 512, 512) fp32. out = x * (x > max(0, 8 neighbors)).
//
// Streaming wave-per-row-strip, v3: PLAIN stores (no nontemporal).
// Evidence from v1/v2 rocprof: both pinned at WRITE_SIZE/dur ~= 1.6-1.7 TB/s
// regardless of structure -> the nt (no-allocate, write-past-L2) store path
// was the saturated resource, and since stores share vmcnt with loads, every
// load-wait drained slow nt stores (VALUBusy 7%, 15k cy/row). Plain stores
// commit to L2 fast and write back as full lines at HBM rate.
//
// One wave owns a full 512-wide row (8 cols/lane as 2x float4) and streams
// a 32-row chunk; vertical 3-row window rolls in registers; horizontal
// neighbors in-register + __shfl at lane seams. No LDS, no __syncthreads.
// Replicate pad via clamped row/col: clamped neighbor == center -> strict >
// fails -> border 0, exactly matching the reference.

#define IMG_W 512
#define IMG_H 512
#define NPLANES 256          // 8 * 32
#define CHUNK 32             // rows per wave-task -> 4096 waves, 16/CU
#define THREADS 256          // 4 waves per block
#define WAVES_PER_BLOCK (THREADS / 64)
#define CHUNKS_PER_PLANE (IMG_H / CHUNK)   // 16

typedef float v4f __attribute__((ext_vector_type(4)));

static_assert(IMG_W == 64 * 8, "one wave covers a full row at 8 floats/lane");
static_assert(IMG_H % CHUNK == 0, "chunks divide evenly");

__device__ __forceinline__ void load_row(const float* __restrict__ base, int r,
                                         float (&d)[8]) {
    const v4f a = *(const v4f*)(base + (size_t)r * IMG_W);
    const v4f b = *(const v4f*)(base + (size_t)r * IMG_W + 4);
    d[0] = a.x; d[1] = a.y; d[2] = a.z; d[3] = a.w;
    d[4] = b.x; d[5] = b.y; d[6] = b.z; d[7] = b.w;
}

// lr[i] = max(left_i, right_i) (center excluded); hm[i] = max(l,c,r).
__device__ __forceinline__ void row_stats(const float (&d)[8], int lane,
                                          float (&lr)[8], float (&hm)[8]) {
    float lnb = __shfl_up(d[7], 1);          // lane-1's col 8l-1
    lnb = (lane == 0) ? d[0] : lnb;          // replicate col 0
    float rnb = __shfl_down(d[0], 1);        // lane+1's col 8l+8
    rnb = (lane == 63) ? d[7] : rnb;         // replicate col 511

    lr[0] = fmaxf(lnb,  d[1]);
    lr[1] = fmaxf(d[0], d[2]);
    lr[2] = fmaxf(d[1], d[3]);
    lr[3] = fmaxf(d[2], d[4]);
    lr[4] = fmaxf(d[3], d[5]);
    lr[5] = fmaxf(d[4], d[6]);
    lr[6] = fmaxf(d[5], d[7]);
    lr[7] = fmaxf(d[6], rnb);
#pragma unroll
    for (int i = 0; i < 8; ++i) hm[i] = fmaxf(lr[i], d[i]);
}

__global__ __launch_bounds__(THREADS, 4)
void nms3x3_kernel(const float* __restrict__ x, float* __restrict__ out) {
    const int wid   = blockIdx.x * WAVES_PER_BLOCK + (threadIdx.x >> 6);
    const int lane  = threadIdx.x & 63;
    const int plane = wid / CHUNKS_PER_PLANE;
    const int chunk = wid % CHUNKS_PER_PLANE;
    const int r0    = chunk * CHUNK;

    const float* img  = x   + (size_t)plane * IMG_H * IMG_W + lane * 8;
    float*       oimg = out + (size_t)plane * IMG_H * IMG_W + lane * 8;

    float pd[8], cd[8], nd[8];
    float pHm[8], cLr[8], cHm[8], nLr[8], nHm[8];
    float junk[8];

    // Prologue: row r0-1 (clamped) -> pHm; row r0 -> cd/cLr/cHm.
    load_row(img, (r0 > 0) ? r0 - 1 : 0, pd);
    row_stats(pd, lane, junk, pHm);
    load_row(img, r0, cd);
    row_stats(cd, lane, cLr, cHm);

#pragma unroll 4
    for (int k = 0; k < CHUNK; ++k) {
        const int r  = r0 + k;
        const int rn = (r + 1 < IMG_H) ? r + 1 : IMG_H - 1;
        load_row(img, rn, nd);
        row_stats(nd, lane, nLr, nHm);

        float o[8];
#pragma unroll
        for (int i = 0; i < 8; ++i) {
            float m = fmaxf(fmaxf(pHm[i], nHm[i]), cLr[i]);
            m = fmaxf(m, 0.0f);                      // center tap zeroed
            o[i] = (cd[i] > m) ? cd[i] : 0.0f;
        }

        *(v4f*)(oimg + (size_t)r * IMG_W)     = (v4f){ o[0], o[1], o[2], o[3] };
        *(v4f*)(oimg + (size_t)r * IMG_W + 4) = (v4f){ o[4], o[5], o[6], o[7] };

#pragma unroll
        for (int i = 0; i < 8; ++i) {
            pHm[i] = cHm[i];
            cd[i]  = nd[i];
            cLr[i] = nLr[i];
            cHm[i] = nHm[i];
        }
    }
}

extern "C" void kernel_launch(void* const* d_in, const int* in_sizes, int n_in,
                              void* d_out, int out_size, void* d_ws, size_t ws_size,
                              hipStream_t stream) {
    const float* x = (const float*)d_in[0];
    float* out     = (float*)d_out;
    const int total_waves = NPLANES * CHUNKS_PER_PLANE;        // 4096
    dim3 grid(total_waves / WAVES_PER_BLOCK);                  // 1024 blocks
    nms3x3_kernel<<<grid, dim3(THREADS), 0, stream>>>(x, out);
}